// Round 5
// baseline (262.928 us; speedup 1.0000x reference)
//
#include <hip/hip_runtime.h>
#include <hip/hip_bf16.h>

#define BATCH 32
#define WDIM 512
#define HDIM 512
#define CDIM 3
#define KPSF 32
#define NPRED (BATCH*WDIM*HDIM*CDIM)  // 25165824

#define TW 56        // tile width  (x): 4 outputs at stride 8 (span 25) + 31 taps
#define TH 63        // tile height (y): 32 + 31
#define TE (TW*TH)   // 3528 per channel
#define TALL (TW*TH*CDIM)  // 10584 dense elements

typedef __bf16 bf16x8 __attribute__((ext_vector_type(8)));
typedef float floatx16 __attribute__((ext_vector_type(16)));
typedef float fx4 __attribute__((ext_vector_type(4)));

// Workgroup barrier that does NOT drain vmcnt: only LDS ordering is required;
// global loads/stores stay in flight across it.
__device__ __forceinline__ void barrier_lgkm() {
    __asm__ volatile("s_waitcnt lgkmcnt(0)\n\ts_barrier" ::: "memory");
}

// Pack psf[b,i,j,0,c] (fp32) into MFMA A-fragment order (bf16):
// dst[((c*32 + j)*2 + h)*64 + lane][t] = psf[b=lane&31][i=16h+8*(lane>>5)+t][j][c]
__global__ __launch_bounds__(64) void pack_psf(const float* __restrict__ psf,
                                               __bf16* __restrict__ dst,
                                               float* __restrict__ loss) {
    if (blockIdx.x == 0 && threadIdx.x == 0) *loss = 0.f;
    int idx = blockIdx.x;              // [0,192) = ((c*32 + j)*2 + h)
    int h = idx & 1;
    int j = (idx >> 1) & 31;
    int c = idx >> 6;
    int lane = threadIdx.x;
    int b = lane & 31;
    int q = lane >> 5;
    bf16x8 v;
#pragma unroll
    for (int t = 0; t < 8; ++t) {
        int i = 16*h + 8*q + t;
        v[t] = (__bf16)psf[((size_t)(b*KPSF + i)*KPSF + j)*CDIM + c];
    }
    *(bf16x8*)(dst + (size_t)(idx*64 + lane)*8) = v;
}

// Block = 192 threads = 3 waves; wave = channel c. Each wave computes 4
// x-positions x0+8s. acc[4] = 64 AGPR; arch VGPRs forced <= 64 via
// __launch_bounds__(192,4) so total unified alloc = 128 -> the HW occupancy
// step gives 4 waves/SIMD = 16 waves/CU (vs 2/SIMD at 129..192 regs).
__global__ __launch_bounds__(192, 4) void conv_mfma(
    const float* __restrict__ obs,    // [B,W,H,C]
    const float* __restrict__ img,    // [W,H,C]
    const __bf16* __restrict__ psfA,  // packed A-frags
    float* __restrict__ out)          // [B,W,H,C] pred, then loss scalar
{
    // sImg (main loop) and sOut (epilogue staging, 12 KB) share the same LDS.
    __shared__ __align__(16) unsigned char smem[CDIM*TE*2];  // 21168 B
    __bf16 (*sImg)[TE] = (__bf16 (*)[TE])smem;
    float* sOut = (float*)smem;

    const int tid  = threadIdx.x;
    const int lane = tid & 63;
    const int c    = tid >> 6;      // wave index = channel
    const int n    = lane & 31;     // MFMA n (y within tile)
    const int q    = lane >> 5;     // k-half selector

    const int bx = blockIdx.x;      // [0,2048)
    const int r8 = bx & 7;          // x mod-8 class
    const int g  = (bx >> 3) & 15;  // 32-wide x group
    const int yt = bx >> 7;         // y tile [0,16)
    const int x0 = g*32 + r8;       // wave's x's = x0 + 8s, s=0..3
    const int ytile = yt*32;

    // ---- stage transposed image tile ----
    const bool interior = (x0 >= 15) && (x0 <= WDIM - 41) &&
                          (ytile >= 15) && (ytile <= HDIM - 48);
    if (interior) {
        // float4 path: per x-row, the 189-float column run starts at a uniform
        // misalignment p2; load alignment-shifted float4 slots, scatter to LDS.
        const int col0 = (ytile - 15)*3;           // >= 0
        const int p2 = col0 & 3;
        const float* gb = img + (size_t)(x0 - 15)*(HDIM*CDIM) + (col0 - p2);
#pragma unroll 2
        for (int f = tid; f < 56*48; f += 192) {
            int r = f / 48;                        // x-row 0..55
            int v = f - r*48;                      // float4 slot 0..47
            fx4 val = *(const fx4*)(gb + (size_t)r*(HDIM*CDIM) + 4*v);
            int d = 4*v - p2;                      // col offset of val[0]
#pragma unroll
            for (int u = 0; u < 4; ++u) {
                int dd = d + u;
                if (dd >= 0 && dd < 189) {
                    int yl = (dd*171) >> 9;        // dd/3 for dd<511
                    int cc = dd - 3*yl;
                    sImg[cc][yl*TW + r] = (__bf16)val[u];
                }
            }
        }
    } else {
#pragma unroll 4
        for (int e = tid; e < TALL; e += 192) {
            int xl = e / (TH*CDIM);
            int rr = e - xl*(TH*CDIM);
            int yl = rr / 3;
            int cc = rr - yl*3;
            int xg = x0 + xl - 15;
            int yg = ytile + yl - 15;
            float v = 0.f;
            if ((unsigned)xg < WDIM && (unsigned)yg < HDIM)
                v = img[((size_t)xg*HDIM + yg)*CDIM + cc];
            sImg[cc][yl*TW + xl] = (__bf16)v;
        }
    }
    __syncthreads();

    // ---- main loop: LDS reads + MFMA, A(j+1) prefetched from L2.
    // No global loads held live here: keeps arch VGPRs <= 64.
    floatx16 acc[4] = {};
    const __bf16* pA = psfA + (size_t)c*(KPSF*2*64*8) + (size_t)lane*8;
    const __bf16* sI = (const __bf16*)&sImg[c][q*8];

    bf16x8 A0 = *(const bf16x8*)(pA);
    bf16x8 A1 = *(const bf16x8*)(pA + 512);
#pragma unroll 2
    for (int j = 0; j < 32; ++j) {
        bf16x8 cA0 = A0, cA1 = A1;
        if (j < 31) {
            A0 = *(const bf16x8*)(pA + (size_t)(j+1)*1024);
            A1 = *(const bf16x8*)(pA + (size_t)(j+1)*1024 + 512);
        }
        const __bf16* rowp = sI + (n + j)*TW;
        bf16x8 C[6];
#pragma unroll
        for (int rr = 0; rr < 6; ++rr)
            C[rr] = *(const bf16x8*)(rowp + rr*8);   // 16B-aligned ds_read_b128
#pragma unroll
        for (int s = 0; s < 4; ++s) {
            acc[s] = __builtin_amdgcn_mfma_f32_32x32x16_bf16(cA0, C[s],   acc[s], 0, 0, 0);
            acc[s] = __builtin_amdgcn_mfma_f32_32x32x16_bf16(cA1, C[s+2], acc[s], 0, 0, 0);
        }
    }

    // ---- epilogue: 4 fully-unrolled LDS transpose rounds (static acc index),
    // lgkm-only barriers; round t handles output x = x0 + 8t. obs loads are
    // depth-1 prefetched inside the epilogue (TLP from 16 waves/CU hides the
    // rest); no obs registers live across the main loop.
    float ls = 0.f;
    unsigned base[4];
#pragma unroll
    for (int k = 0; k < 4; ++k) {
        int f = tid + 192*k;                    // float4 index [0,768)
        int fb = f / 24;                        // batch
        int r4 = (f - fb*24) * 4;               // offset in 96-float (y,c) run
        base[k] = ((unsigned)(fb*WDIM + x0)*HDIM + (unsigned)ytile)*CDIM + r4;
    }
    fx4 ob[4];
#pragma unroll
    for (int k = 0; k < 4; ++k)
        ob[k] = __builtin_nontemporal_load((const fx4*)&obs[base[k]]);

#pragma unroll
    for (int t = 0; t < 4; ++t) {
        barrier_lgkm();    // all waves' prior LDS reads complete (LDS only)
#pragma unroll
        for (int rr = 0; rr < 16; ++rr) {
            int b = (rr & 3) + 8*(rr >> 2) + 4*q;   // D row = batch
            sOut[(b*32 + n)*3 + c] = acc[t][rr];    // bank 3n+c: conflict-free
        }
        barrier_lgkm();    // sOut writes visible (LDS only)
        fx4 cur[4];
#pragma unroll
        for (int k = 0; k < 4; ++k) cur[k] = ob[k];
        if (t < 3) {       // depth-1 prefetch of next round's obs
#pragma unroll
            for (int k = 0; k < 4; ++k)
                ob[k] = __builtin_nontemporal_load(
                    (const fx4*)&obs[base[k] + (unsigned)(t+1)*8*HDIM*CDIM]);
        }
#pragma unroll
        for (int k = 0; k < 4; ++k) {
            fx4 p = *(const fx4*)&sOut[4*(tid + 192*k)];
            __builtin_nontemporal_store(p, (fx4*)&out[base[k] + (unsigned)t*8*HDIM*CDIM]);
            fx4 d = cur[k] - p;
            ls += d[0]*d[0] + d[1]*d[1] + d[2]*d[2] + d[3]*d[3];
        }
    }

#pragma unroll
    for (int m = 32; m >= 1; m >>= 1) ls += __shfl_xor(ls, m, 64);
    if (lane == 0) atomicAdd(out + NPRED, ls * (1.0f/(float)NPRED));
}

extern "C" void kernel_launch(void* const* d_in, const int* in_sizes, int n_in,
                              void* d_out, int out_size, void* d_ws, size_t ws_size,
                              hipStream_t stream) {
    const float* obs = (const float*)d_in[0];   // observed_images [32,512,512,3]
    const float* img = (const float*)d_in[1];   // estimated_image [512,512,3]
    const float* psf = (const float*)d_in[2];   // psfs [32,32,32,1,3]
    float* out = (float*)d_out;                 // pred (25165824) + loss (1)
    __bf16* psfA = (__bf16*)d_ws;               // 196608 B packed psf frags

    pack_psf<<<192, 64, 0, stream>>>(psf, psfA, out + NPRED);
    conv_mfma<<<2048, 192, 0, stream>>>(obs, img, psfA, out);
}

// Round 7
// 257.963 us; speedup vs baseline: 1.0192x; 1.0192x over previous
//
#include <hip/hip_runtime.h>
#include <hip/hip_bf16.h>

#define BATCH 32
#define WDIM 512
#define HDIM 512
#define CDIM 3
#define KPSF 32
#define NPRED (BATCH*WDIM*HDIM*CDIM)  // 25165824

#define TW 56        // tile width  (x): 4 outputs at stride 8 (span 25) + 31 taps
#define TH 63        // tile height (y): 32 + 31
#define TE (TW*TH)   // 3528 per channel
#define TALL (TW*TH*CDIM)  // 10584 dense elements

// LDS map: sImg/sOut share [0, 21168); A-rings at [21168, 51888):
// per-wave ring = 5 slots x 2048 B (slot = A0|A1 halves of one j).
#define RING_OFF 21168
#define RING_PER_WAVE 10240
#define LDS_BYTES (RING_OFF + CDIM*RING_PER_WAVE)   // 51888

typedef __bf16 bf16x8 __attribute__((ext_vector_type(8)));
typedef float floatx16 __attribute__((ext_vector_type(16)));
typedef float fx4 __attribute__((ext_vector_type(4)));

// Workgroup barrier that does NOT drain vmcnt: only LDS ordering is required;
// global loads (incl. the A-ring global_load_lds) stay in flight across it.
__device__ __forceinline__ void barrier_lgkm() {
    __asm__ volatile("s_waitcnt lgkmcnt(0)\n\ts_barrier" ::: "memory");
}

// Async global->LDS (16 B per lane). LDS dest must be wave-uniform; HW adds
// lane*16. Our psfA pack layout matches this exactly.
__device__ __forceinline__ void ldsA(const void* g, void* l) {
    __builtin_amdgcn_global_load_lds(
        (const __attribute__((address_space(1))) void*)g,
        (__attribute__((address_space(3))) void*)l, 16, 0, 0);
}

// Pack psf[b,i,j,0,c] (fp32) into MFMA A-fragment order (bf16):
// dst[((c*32 + j)*2 + h)*64 + lane][t] = psf[b=lane&31][i=16h+8*(lane>>5)+t][j][c]
__global__ __launch_bounds__(64) void pack_psf(const float* __restrict__ psf,
                                               __bf16* __restrict__ dst,
                                               float* __restrict__ loss) {
    if (blockIdx.x == 0 && threadIdx.x == 0) *loss = 0.f;
    int idx = blockIdx.x;              // [0,192) = ((c*32 + j)*2 + h)
    int h = idx & 1;
    int j = (idx >> 1) & 31;
    int c = idx >> 6;
    int lane = threadIdx.x;
    int b = lane & 31;
    int q = lane >> 5;
    bf16x8 v;
#pragma unroll
    for (int t = 0; t < 8; ++t) {
        int i = 16*h + 8*q + t;
        v[t] = (__bf16)psf[((size_t)(b*KPSF + i)*KPSF + j)*CDIM + c];
    }
    *(bf16x8*)(dst + (size_t)(idx*64 + lane)*8) = v;
}

// Block = 192 threads = 3 waves; wave = channel c; 4 x-positions per wave.
// A-fragments stream through a per-wave LDS ring (global_load_lds, depth 5,
// counted vmcnt(6) -> never drains) so psfA L2/L3 latency is off the critical
// path regardless of cache eviction by the obs/out streams.
__global__ __launch_bounds__(192, 3) void conv_mfma(
    const float* __restrict__ obs,    // [B,W,H,C]
    const float* __restrict__ img,    // [W,H,C]
    const __bf16* __restrict__ psfA,  // packed A-frags
    float* __restrict__ out)          // [B,W,H,C] pred, then loss scalar
{
    __shared__ __align__(16) unsigned char smem[LDS_BYTES];
    __bf16 (*sImg)[TE] = (__bf16 (*)[TE])smem;
    float* sOut = (float*)smem;

    const int tid  = threadIdx.x;
    const int lane = tid & 63;
    const int c    = tid >> 6;      // wave index = channel
    const int n    = lane & 31;     // MFMA n (y within tile)
    const int q    = lane >> 5;     // k-half selector

    const int bx = blockIdx.x;      // [0,2048)
    const int r8 = bx & 7;          // x mod-8 class
    const int g  = (bx >> 3) & 15;  // 32-wide x group
    const int yt = bx >> 7;         // y tile [0,16)
    const int x0 = g*32 + r8;       // wave's x's = x0 + 8s, s=0..3
    const int ytile = yt*32;

    // ---- A-ring prologue: issue slots 0..3 (8 loads) before staging, so they
    // fly under the stage + barrier. psfA byte layout: c*65536 + j*2048 +
    // h*1024 + lane*16 == ring slot layout.
    const char* gA   = (const char*)psfA + (size_t)c*65536 + (size_t)(lane*16);
    char* ringU      = (char*)smem + RING_OFF + c*RING_PER_WAVE;  // wave-uniform
    const char* ringL = ringU + lane*16;                          // lane read addr
#pragma unroll
    for (int s0 = 0; s0 < 4; ++s0) {
        ldsA(gA + s0*2048,        ringU + s0*2048);
        ldsA(gA + s0*2048 + 1024, ringU + s0*2048 + 1024);
    }

    // ---- stage transposed image tile ----
    const bool interior = (x0 >= 15) && (x0 <= WDIM - 41) &&
                          (ytile >= 15) && (ytile <= HDIM - 48);
    if (interior) {
        // float4 path: per x-row, the 189-float column run starts at a uniform
        // misalignment p2; load alignment-shifted float4 slots, scatter to LDS.
        const int col0 = (ytile - 15)*3;           // >= 0
        const int p2 = col0 & 3;
        const float* gb = img + (size_t)(x0 - 15)*(HDIM*CDIM) + (col0 - p2);
#pragma unroll 2
        for (int f = tid; f < 56*48; f += 192) {
            int r = f / 48;                        // x-row 0..55
            int v = f - r*48;                      // float4 slot 0..47
            fx4 val = *(const fx4*)(gb + (size_t)r*(HDIM*CDIM) + 4*v);
            int d = 4*v - p2;                      // col offset of val[0]
#pragma unroll
            for (int u = 0; u < 4; ++u) {
                int dd = d + u;
                if (dd >= 0 && dd < 189) {
                    int yl = (dd*171) >> 9;        // dd/3 for dd<511
                    int cc = dd - 3*yl;
                    sImg[cc][yl*TW + r] = (__bf16)val[u];
                }
            }
        }
    } else {
#pragma unroll 4
        for (int e = tid; e < TALL; e += 192) {
            int xl = e / (TH*CDIM);
            int rr = e - xl*(TH*CDIM);
            int yl = rr / 3;
            int cc = rr - yl*3;
            int xg = x0 + xl - 15;
            int yg = ytile + yl - 15;
            float v = 0.f;
            if ((unsigned)xg < WDIM && (unsigned)yg < HDIM)
                v = img[((size_t)xg*HDIM + yg)*CDIM + cc];
            sImg[cc][yl*TW + xl] = (__bf16)v;
        }
    }
    barrier_lgkm();   // LDS-only barrier: ring loads stay in flight

    // ---- main loop: C from sImg (LDS), A from the ring (LDS), MFMA.
    // No direct global loads on the critical path.
    floatx16 acc[4] = {};
    const __bf16* sI = (const __bf16*)&sImg[c][q*8];

    asm volatile("s_waitcnt vmcnt(6)" ::: "memory");   // slot 0 landed
    bf16x8 Ac0 = *(const bf16x8*)(ringL);
    bf16x8 Ac1 = *(const bf16x8*)(ringL + 1024);
    int rd = 2048;     // slot (j+1) read offset
    int wr = 8192;     // slot (j+4) write offset
#pragma unroll 2
    for (int j = 0; j < 32; ++j) {
        const __bf16* rowp = sI + (n + j)*TW;
        bf16x8 C[6];
#pragma unroll
        for (int rr = 0; rr < 6; ++rr)
            C[rr] = *(const bf16x8*)(rowp + rr*8);   // 16B-aligned ds_read_b128
#pragma unroll
        for (int s = 0; s < 4; ++s) {
            acc[s] = __builtin_amdgcn_mfma_f32_32x32x16_bf16(Ac0, C[s],   acc[s], 0, 0, 0);
            acc[s] = __builtin_amdgcn_mfma_f32_32x32x16_bf16(Ac1, C[s+2], acc[s], 0, 0, 0);
        }
        // issue slot j+4 (tail wraps: dummy re-loads keep vmcnt counts uniform)
        int js = ((j + 4) & 31)*2048;
        ldsA(gA + js,        ringU + wr);
        ldsA(gA + js + 1024, ringU + wr + 1024);
        // counted wait: all but newest 6 -> slot j+1 complete; never drains
        asm volatile("s_waitcnt vmcnt(6)" ::: "memory");
        bf16x8 An0 = *(const bf16x8*)(ringL + rd);
        bf16x8 An1 = *(const bf16x8*)(ringL + rd + 1024);
        rd += 2048; if (rd == RING_PER_WAVE) rd = 0;
        wr += 2048; if (wr == RING_PER_WAVE) wr = 0;
        Ac0 = An0; Ac1 = An1;
    }

    // ---- epilogue: 4 fully-unrolled LDS transpose rounds (static acc index),
    // lgkm-only barriers; round t handles output x = x0 + 8t.
    float ls = 0.f;
    unsigned base[4];
#pragma unroll
    for (int k = 0; k < 4; ++k) {
        int f = tid + 192*k;                    // float4 index [0,768)
        int fb = f / 24;                        // batch
        int r4 = (f - fb*24) * 4;               // offset in 96-float (y,c) run
        base[k] = ((unsigned)(fb*WDIM + x0)*HDIM + (unsigned)ytile)*CDIM + r4;
    }
    fx4 ob[4];
#pragma unroll
    for (int k = 0; k < 4; ++k)
        ob[k] = __builtin_nontemporal_load((const fx4*)&obs[base[k]]);

#pragma unroll
    for (int t = 0; t < 4; ++t) {
        barrier_lgkm();    // all waves' prior LDS reads complete (LDS only)
#pragma unroll
        for (int rr = 0; rr < 16; ++rr) {
            int b = (rr & 3) + 8*(rr >> 2) + 4*q;   // D row = batch
            sOut[(b*32 + n)*3 + c] = acc[t][rr];    // bank 3n+c: conflict-free
        }
        barrier_lgkm();    // sOut writes visible (LDS only)
        fx4 cur[4];
#pragma unroll
        for (int k = 0; k < 4; ++k) cur[k] = ob[k];
        if (t < 3) {       // depth-1 prefetch of next round's obs
#pragma unroll
            for (int k = 0; k < 4; ++k)
                ob[k] = __builtin_nontemporal_load(
                    (const fx4*)&obs[base[k] + (unsigned)(t+1)*8*HDIM*CDIM]);
        }
#pragma unroll
        for (int k = 0; k < 4; ++k) {
            fx4 p = *(const fx4*)&sOut[4*(tid + 192*k)];
            __builtin_nontemporal_store(p, (fx4*)&out[base[k] + (unsigned)t*8*HDIM*CDIM]);
            fx4 d = cur[k] - p;
            ls += d[0]*d[0] + d[1]*d[1] + d[2]*d[2] + d[3]*d[3];
        }
    }

#pragma unroll
    for (int m = 32; m >= 1; m >>= 1) ls += __shfl_xor(ls, m, 64);
    if (lane == 0) atomicAdd(out + NPRED, ls * (1.0f/(float)NPRED));
}

extern "C" void kernel_launch(void* const* d_in, const int* in_sizes, int n_in,
                              void* d_out, int out_size, void* d_ws, size_t ws_size,
                              hipStream_t stream) {
    const float* obs = (const float*)d_in[0];   // observed_images [32,512,512,3]
    const float* img = (const float*)d_in[1];   // estimated_image [512,512,3]
    const float* psf = (const float*)d_in[2];   // psfs [32,32,32,1,3]
    float* out = (float*)d_out;                 // pred (25165824) + loss (1)
    __bf16* psfA = (__bf16*)d_ws;               // 196608 B packed psf frags

    pack_psf<<<192, 64, 0, stream>>>(psf, psfA, out + NPRED);
    conv_mfma<<<2048, 192, 0, stream>>>(obs, img, psfA, out);
}

// Round 8
// 251.982 us; speedup vs baseline: 1.0434x; 1.0237x over previous
//
#include <hip/hip_runtime.h>
#include <hip/hip_bf16.h>

#define BATCH 32
#define WDIM 512
#define HDIM 512
#define CDIM 3
#define KPSF 32
#define NPRED (BATCH*WDIM*HDIM*CDIM)  // 25165824

#define TW 56        // tile width  (x): 4 outputs at stride 8 (span 25) + 31 taps
#define TH 63        // tile height (y): 32 + 31
#define TE (TW*TH)   // 3528 per channel
#define TALL (TW*TH*CDIM)  // 10584 dense elements

typedef __bf16 bf16x8 __attribute__((ext_vector_type(8)));
typedef float floatx16 __attribute__((ext_vector_type(16)));
typedef float fx4 __attribute__((ext_vector_type(4)));

// Workgroup barrier that does NOT drain vmcnt: only LDS ordering is required;
// global loads/stores stay in flight across it.
__device__ __forceinline__ void barrier_lgkm() {
    __asm__ volatile("s_waitcnt lgkmcnt(0)\n\ts_barrier" ::: "memory");
}

// Pack psf[b,i,j,0,c] (fp32) into MFMA A-fragment order (bf16):
// dst[((c*32 + j)*2 + h)*64 + lane][t] = psf[b=lane&31][i=16h+8*(lane>>5)+t][j][c]
__global__ __launch_bounds__(64) void pack_psf(const float* __restrict__ psf,
                                               __bf16* __restrict__ dst,
                                               float* __restrict__ loss) {
    if (blockIdx.x == 0 && threadIdx.x == 0) *loss = 0.f;
    int idx = blockIdx.x;              // [0,192) = ((c*32 + j)*2 + h)
    int h = idx & 1;
    int j = (idx >> 1) & 31;
    int c = idx >> 6;
    int lane = threadIdx.x;
    int b = lane & 31;
    int q = lane >> 5;
    bf16x8 v;
#pragma unroll
    for (int t = 0; t < 8; ++t) {
        int i = 16*h + 8*q + t;
        v[t] = (__bf16)psf[((size_t)(b*KPSF + i)*KPSF + j)*CDIM + c];
    }
    *(bf16x8*)(dst + (size_t)(idx*64 + lane)*8) = v;
}

// Block = 192 threads = 3 waves; wave = channel c. Each wave computes 4
// x-positions x0+8s. R3 structure (best measured: 118.5 us), single change:
// all nontemporal hints removed — obs/out go through the normal cache path.
__global__ __launch_bounds__(192, 3) void conv_mfma(
    const float* __restrict__ obs,    // [B,W,H,C]
    const float* __restrict__ img,    // [W,H,C]
    const __bf16* __restrict__ psfA,  // packed A-frags
    float* __restrict__ out)          // [B,W,H,C] pred, then loss scalar
{
    // sImg (main loop) and sOut (epilogue staging, 12 KB) share the same LDS.
    __shared__ __align__(16) unsigned char smem[CDIM*TE*2];  // 21168 B
    __bf16 (*sImg)[TE] = (__bf16 (*)[TE])smem;
    float* sOut = (float*)smem;

    const int tid  = threadIdx.x;
    const int lane = tid & 63;
    const int c    = tid >> 6;      // wave index = channel
    const int n    = lane & 31;     // MFMA n (y within tile)
    const int q    = lane >> 5;     // k-half selector

    const int bx = blockIdx.x;      // [0,2048)
    const int r8 = bx & 7;          // x mod-8 class
    const int g  = (bx >> 3) & 15;  // 32-wide x group
    const int yt = bx >> 7;         // y tile [0,16)
    const int x0 = g*32 + r8;       // wave's x's = x0 + 8s, s=0..3
    const int ytile = yt*32;

    // ---- stage transposed image tile ----
    const bool interior = (x0 >= 15) && (x0 <= WDIM - 41) &&
                          (ytile >= 15) && (ytile <= HDIM - 48);
    if (interior) {
        // float4 path: per x-row, the 189-float column run starts at a uniform
        // misalignment p2; load alignment-shifted float4 slots, scatter to LDS.
        const int col0 = (ytile - 15)*3;           // >= 0
        const int p2 = col0 & 3;
        const float* gb = img + (size_t)(x0 - 15)*(HDIM*CDIM) + (col0 - p2);
#pragma unroll 2
        for (int f = tid; f < 56*48; f += 192) {
            int r = f / 48;                        // x-row 0..55
            int v = f - r*48;                      // float4 slot 0..47
            fx4 val = *(const fx4*)(gb + (size_t)r*(HDIM*CDIM) + 4*v);
            int d = 4*v - p2;                      // col offset of val[0]
#pragma unroll
            for (int u = 0; u < 4; ++u) {
                int dd = d + u;
                if (dd >= 0 && dd < 189) {
                    int yl = (dd*171) >> 9;        // dd/3 for dd<511
                    int cc = dd - 3*yl;
                    sImg[cc][yl*TW + r] = (__bf16)val[u];
                }
            }
        }
    } else {
#pragma unroll 4
        for (int e = tid; e < TALL; e += 192) {
            int xl = e / (TH*CDIM);
            int rr = e - xl*(TH*CDIM);
            int yl = rr / 3;
            int cc = rr - yl*3;
            int xg = x0 + xl - 15;
            int yg = ytile + yl - 15;
            float v = 0.f;
            if ((unsigned)xg < WDIM && (unsigned)yg < HDIM)
                v = img[((size_t)xg*HDIM + yg)*CDIM + cc];
            sImg[cc][yl*TW + xl] = (__bf16)v;
        }
    }
    __syncthreads();

    // ---- issue-early obs loads for epilogue round 0 (hidden under main) ----
    unsigned base[4];
#pragma unroll
    for (int k = 0; k < 4; ++k) {
        int f = tid + 192*k;                    // float4 index [0,768)
        int fb = f / 24;                        // batch
        int r4 = (f - fb*24) * 4;               // offset in 96-float (y,c) run
        base[k] = ((unsigned)(fb*WDIM + x0)*HDIM + (unsigned)ytile)*CDIM + r4;
    }
    fx4 obA[4];
#pragma unroll
    for (int k = 0; k < 4; ++k)
        obA[k] = *(const fx4*)&obs[base[k]];

    // ---- main loop: LDS reads + MFMA, A(j+1) prefetched from L2 ----
    floatx16 acc[4] = {};
    const __bf16* pA = psfA + (size_t)c*(KPSF*2*64*8) + (size_t)lane*8;
    const __bf16* sI = (const __bf16*)&sImg[c][q*8];

    bf16x8 A0 = *(const bf16x8*)(pA);
    bf16x8 A1 = *(const bf16x8*)(pA + 512);
#pragma unroll 2
    for (int j = 0; j < 32; ++j) {
        bf16x8 cA0 = A0, cA1 = A1;
        if (j < 31) {
            A0 = *(const bf16x8*)(pA + (size_t)(j+1)*1024);
            A1 = *(const bf16x8*)(pA + (size_t)(j+1)*1024 + 512);
        }
        const __bf16* rowp = sI + (n + j)*TW;
        bf16x8 C[6];
#pragma unroll
        for (int rr = 0; rr < 6; ++rr)
            C[rr] = *(const bf16x8*)(rowp + rr*8);   // 16B-aligned ds_read_b128
#pragma unroll
        for (int s = 0; s < 4; ++s) {
            acc[s] = __builtin_amdgcn_mfma_f32_32x32x16_bf16(cA0, C[s],   acc[s], 0, 0, 0);
            acc[s] = __builtin_amdgcn_mfma_f32_32x32x16_bf16(cA1, C[s+2], acc[s], 0, 0, 0);
        }
    }

    // ---- epilogue: 4 fully-unrolled LDS transpose rounds (static acc index),
    // lgkm-only barriers; round t handles output x = x0 + 8t.
    float ls = 0.f;
    fx4 obB[4];
#pragma unroll
    for (int k = 0; k < 4; ++k)
        obB[k] = *(const fx4*)&obs[base[k] + 8*HDIM*CDIM];

#pragma unroll
    for (int t = 0; t < 4; ++t) {
        barrier_lgkm();    // all waves' prior LDS reads complete (LDS only)
#pragma unroll
        for (int rr = 0; rr < 16; ++rr) {
            int b = (rr & 3) + 8*(rr >> 2) + 4*q;   // D row = batch
            sOut[(b*32 + n)*3 + c] = acc[t][rr];    // bank 3n+c: conflict-free
        }
        barrier_lgkm();    // sOut writes visible (LDS only)
        fx4 cur[4];
#pragma unroll
        for (int k = 0; k < 4; ++k) { cur[k] = obA[k]; obA[k] = obB[k]; }
        if (t < 2) {       // depth-2 prefetch covers HBM/L3 latency
#pragma unroll
            for (int k = 0; k < 4; ++k)
                obB[k] = *(const fx4*)&obs[base[k] + (unsigned)(t+2)*8*HDIM*CDIM];
        }
#pragma unroll
        for (int k = 0; k < 4; ++k) {
            fx4 p = *(const fx4*)&sOut[4*(tid + 192*k)];
            *(fx4*)&out[base[k] + (unsigned)t*8*HDIM*CDIM] = p;
            fx4 d = cur[k] - p;
            ls += d[0]*d[0] + d[1]*d[1] + d[2]*d[2] + d[3]*d[3];
        }
    }

#pragma unroll
    for (int m = 32; m >= 1; m >>= 1) ls += __shfl_xor(ls, m, 64);
    if (lane == 0) atomicAdd(out + NPRED, ls * (1.0f/(float)NPRED));
}

extern "C" void kernel_launch(void* const* d_in, const int* in_sizes, int n_in,
                              void* d_out, int out_size, void* d_ws, size_t ws_size,
                              hipStream_t stream) {
    const float* obs = (const float*)d_in[0];   // observed_images [32,512,512,3]
    const float* img = (const float*)d_in[1];   // estimated_image [512,512,3]
    const float* psf = (const float*)d_in[2];   // psfs [32,32,32,1,3]
    float* out = (float*)d_out;                 // pred (25165824) + loss (1)
    __bf16* psfA = (__bf16*)d_ws;               // 196608 B packed psf frags

    pack_psf<<<192, 64, 0, stream>>>(psf, psfA, out + NPRED);
    conv_mfma<<<2048, 192, 0, stream>>>(obs, img, psfA, out);
}